// Round 12
// baseline (50.392 us; speedup 1.0000x reference)
//
#include <hip/hip_runtime.h>

// Bilinear warp: out[b,c,h,w] = bilerp(img[b,c], (w+flo[b,0,h,w], h+flo[b,1,h,w]))
// img: [8,16,512,512] f32, flo: [8,2,512,512] f32, out: [8,16,512,512] f32.
//
// Round 12: geometry-only change on the R9/R11 structure. Tile 64x32 with
// 256 threads (8 px/thread = 2 rows x 4 cols), window 48x84 (pitch 84) = 16
// chunks -> 4 stage instr/wave/channel (even split across 4 waves).
// VMEM/wave: 100 per 512 px (0.195/px, was 0.258); staged bytes 393->268MB
// (halo amp 1.97 vs 2.71). Keeps: NBUF=3, 1 barrier/channel, counted vmcnt,
// NT stores, XCD-batch swizzle, per-row ox-skew. This isolates R8's
// confound (R8 bundled 8-wave barriers + regular stores; here: 4 waves, NT).

#define BB 8
#define CC 16
#define HH 512
#define WW 512
#define HWSZ (HH * WW)

#define TW 64                    // output tile width
#define TH 32                    // output tile height
#define TILES_X (WW / TW)        // 8
#define TILES_Y (HH / TH)        // 16
#define TPI (TILES_X * TILES_Y)  // 128
#define NBLOCKS (BB * TPI)       // 1024 = 8 * 128 (XCD k <- batch k, bijective)
#define NXCD 8

#define HALO_T 7                 // top halo rows (window rows 48 = 7+32+9)
#define HALO_L 8                 // nominal left halo
#define LDS_PITCH 84             // floats per LDS row; row rr holds global
                                 //  cols [ox(rr), ox(rr)+83]
#define OXMAX (WW - LDS_PITCH)   // 428
#define WIN_ROWS 48              // rows 0..47 staged (48*84=4032)
#define PAD_FLOATS 4096          // 16 chunks * 256 floats (tail rows unread)
#define NBUF 3                   // triple buffer, single barrier per channel

typedef float f4 __attribute__((ext_vector_type(4)));

__device__ __forceinline__ void gload_lds16(const float* g, float* l) {
    // per-lane global src; wave-uniform LDS base, HW writes base + lane*16
    __builtin_amdgcn_global_load_lds(
        (const __attribute__((address_space(1))) void*)g,
        (__attribute__((address_space(3))) void*)l,
        16, 0, 0);
}

__global__ __launch_bounds__(256) void warp_bilinear_kernel(
    const float* __restrict__ img,
    const float* __restrict__ flo,
    float* __restrict__ out)
{
    __shared__ __align__(16) float lds[NBUF * PAD_FLOATS];   // 48 KB

    // XCD swizzle: XCD k <- batch k, tiles top-to-bottom.
    int bid = blockIdx.x;
    int wk  = (bid % NXCD) * (NBLOCKS / NXCD) + bid / NXCD;
    int b    = wk / TPI;
    int tile = wk - b * TPI;
    int ty   = tile / TILES_X;
    int tx   = tile - ty * TILES_X;

    int t    = threadIdx.x;
    int wv   = t >> 6;               // wave id 0..3
    int lane = t & 63;

    int r   = t >> 4;                // row-pair base 0..15: rows r and r+16
    int c4  = (t & 15) << 2;         // col in tile, 4 px per row-pair half
    int h0  = ty * TH + r;           // first row
    int h1  = h0 + 16;               // second row
    int w0  = tx * TW + c4;
    int hw0 = h0 * WW + w0;
    int hw1 = h1 * WW + w0;
    int wx0 = tx * TW - HALO_L;      // nominal window origin (may be <0)
    int wy0 = ty * TH - HALO_T;

    const float* imgb = img + (size_t)b * CC * HWSZ;
    float*       outb = out + (size_t)b * CC * HWSZ;

    // ---- flo loads FIRST: their implicit wait leaves prefetch in flight ---
    f4 fx4a = *(const f4*)(flo + (size_t)(b * 2 + 0) * HWSZ + hw0);
    f4 fx4b = *(const f4*)(flo + (size_t)(b * 2 + 0) * HWSZ + hw1);
    f4 fy4a = *(const f4*)(flo + (size_t)(b * 2 + 1) * HWSZ + hw0);
    f4 fy4b = *(const f4*)(flo + (size_t)(b * 2 + 1) * HWSZ + hw1);

    // ---- staging chunk setup: wave wv stages chunks {wv,wv+4,wv+8,wv+12} --
    // LDS float f: rr=f/84, cc=f%84 (mult of 4; 84%4==0 so 16B groups never
    // straddle rows). Row rr holds global cols [ox(rr), ox(rr)+83], all
    // in-bounds (ox<=428). Skew: ox = clamp(wx0-(rr&3)) -> consecutive rows
    // occupy disjoint bank quarters (per-instruction rows differ by r&3).
    const float* srcp[4];            // per-lane global src, channel 0
    int          loff[4];            // LDS float offset (wave-uniform)
    #pragma unroll
    for (int j = 0; j < 4; ++j) {
        int k  = wv + 4 * j;
        int f  = k * 256 + lane * 4;            // float idx in buffer (mult of 4)
        int rr = f / LDS_PITCH;                 // LDS row (rows >=48 unread)
        int cc = f - rr * LDS_PITCH;            // 0..80, mult of 4
        int gy = min(max(wy0 + rr, 0), HH - 1); // whole-row y clamp
        int ox = min(max(wx0 - (rr & 3), 0), OXMAX);   // skewed row origin
        srcp[j] = imgb + gy * WW + ox + cc;
        loff[j] = k * 256;
    }

    auto stage = [&](int ch, int buf) {
        const size_t choff = (size_t)ch * HWSZ;
        float* lbase = lds + buf * PAD_FLOATS;
        #pragma unroll
        for (int j = 0; j < 4; ++j)
            gload_lds16(srcp[j] + choff, lbase + loff[j]);
    };

    stage(0, 0);   // 2-deep prefetch in flight before any dependent work
    stage(1, 1);

    // ---- per-pixel precompute, 8 px (2 rows x 4 cols) ---------------------
    int   o0[8], o1[8];
    float wtx[8], wty[8], wbx[8], wby[8];
    int   badmask = 0;
    #pragma unroll
    for (int p = 0; p < 2; ++p) {
        int hp = p ? h1 : h0;
        #pragma unroll
        for (int i = 0; i < 4; ++i) {
            int idx = p * 4 + i;
            float fx = p ? fx4b[i] : fx4a[i];
            float fy = p ? fy4b[i] : fy4a[i];
            float pos_x = (float)(w0 + i) + fx;
            float pos_y = (float)hp + fy;

            float x0f = floorf(pos_x);
            float y0f = floorf(pos_y);
            float xw  = pos_x - x0f;   // weights from UNclamped floor (reference)
            float yw  = pos_y - y0f;

            int x0 = (int)fminf(fmaxf(x0f,        0.0f), (float)(WW - 1));
            int x1 = (int)fminf(fmaxf(x0f + 1.0f, 0.0f), (float)(WW - 1));
            int y0 = (int)fminf(fmaxf(y0f,        0.0f), (float)(HH - 1));
            int y1 = (int)fminf(fmaxf(y0f + 1.0f, 0.0f), (float)(HH - 1));

            int xb = min(x0, WW - 2);  // merged pair [xb, xb+1]

            float wa = (1.0f - xw) * (1.0f - yw);
            float wb = (1.0f - xw) * yw;
            float wc = xw * (1.0f - yw);
            float wd = xw * yw;

            float tx_ = (x0 == xb ? wa : 0.0f) + (x1 == xb ? wc : 0.0f);
            float bx_ = (x0 == xb ? wb : 0.0f) + (x1 == xb ? wd : 0.0f);
            wtx[idx] = tx_;  wty[idx] = (wa + wc) - tx_;
            wbx[idx] = bx_;  wby[idx] = (wb + wd) - bx_;

            int r0 = y0 - wy0, r1 = y1 - wy0;
            int ox0 = min(max(wx0 - (r0 & 3), 0), OXMAX);  // same as stage
            int ox1 = min(max(wx0 - (r1 & 3), 0), OXMAX);
            int s0 = xb - ox0, s1 = xb - ox1;
            bool ok = (s0 >= 0) & (s0 <= LDS_PITCH - 2)
                    & (s1 >= 0) & (s1 <= LDS_PITCH - 2)
                    & (r0 >= 0) & (r1 <= WIN_ROWS - 1);
            int a0 = r0 * LDS_PITCH + s0;
            int a1 = r1 * LDS_PITCH + s1;
            if (!ok) { a0 = 0; a1 = 0; badmask |= (1 << idx); }
            o0[idx] = a0;  o1[idx] = a1;
        }
    }

    // ---- channel loop: ONE barrier per channel, stage 2 ahead -------------
    // Per-wave VMEM issue: [flo x4][stage0 x4][stage1 x4] | iter c:
    // store(c) x2, stage(c+2) x4. At iter-c wait, ops newer than stage(c):
    //   c==0 : stage(1) x4                    -> vmcnt(4)
    //   1..14: store(c-1) x2 + stage(c+1) x4  -> vmcnt(6)  (stores in flight)
    //   c==15: store(14) x2                   -> vmcnt(2)
    #pragma unroll
    for (int c = 0; c < CC; ++c) {
        const int buf = c % NBUF;

        if (c == 0)          asm volatile("s_waitcnt vmcnt(4)" ::: "memory");
        else if (c < CC - 1) asm volatile("s_waitcnt vmcnt(6)" ::: "memory");
        else                 asm volatile("s_waitcnt vmcnt(2)" ::: "memory");
        asm volatile("s_waitcnt lgkmcnt(0)" ::: "memory"); // reads of c-1 drained
        __builtin_amdgcn_sched_barrier(0);
        __builtin_amdgcn_s_barrier();   // stage(c) visible AND all waves done
                                        // reading buf((c-1)%3)

        const float* cur = lds + buf * PAD_FLOATS;
        f4 va, vb;
        #pragma unroll
        for (int i = 0; i < 4; ++i) {
            float t0 = cur[o0[i]];
            float t1 = cur[o0[i] + 1];
            float u0 = cur[o1[i]];
            float u1 = cur[o1[i] + 1];
            va[i] = wtx[i] * t0 + wty[i] * t1 + wbx[i] * u0 + wby[i] * u1;
        }
        #pragma unroll
        for (int i = 0; i < 4; ++i) {
            float t0 = cur[o0[4 + i]];
            float t1 = cur[o0[4 + i] + 1];
            float u0 = cur[o1[4 + i]];
            float u1 = cur[o1[4 + i] + 1];
            vb[i] = wtx[4 + i] * t0 + wty[4 + i] * t1
                  + wbx[4 + i] * u0 + wby[4 + i] * u1;
        }
        __builtin_nontemporal_store(va, (f4*)(outb + (size_t)c * HWSZ + hw0));
        __builtin_nontemporal_store(vb, (f4*)(outb + (size_t)c * HWSZ + hw1));

        if (c + 2 < CC) stage(c + 2, (c + 2) % NBUF);  // overwrites buf((c-1)%3)
    }

    // ---- fixup: pixels whose footprint missed the staged window (~never) ---
    if (__builtin_expect(badmask != 0, 0)) {
        #pragma unroll
        for (int idx = 0; idx < 8; ++idx) if (badmask & (1 << idx)) {
            int p  = idx >> 2, i = idx & 3;
            int hp = p ? h1 : h0;
            int hwp = p ? hw1 : hw0;
            float fx = flo[(size_t)(b * 2 + 0) * HWSZ + hwp + i];
            float fy = flo[(size_t)(b * 2 + 1) * HWSZ + hwp + i];
            float pos_x = (float)(w0 + i) + fx;
            float pos_y = (float)hp + fy;
            float x0f = floorf(pos_x), y0f = floorf(pos_y);
            float xw = pos_x - x0f,   yw = pos_y - y0f;
            int x0 = (int)fminf(fmaxf(x0f,        0.0f), (float)(WW - 1));
            int x1 = (int)fminf(fmaxf(x0f + 1.0f, 0.0f), (float)(WW - 1));
            int y0 = (int)fminf(fmaxf(y0f,        0.0f), (float)(HH - 1));
            int y1 = (int)fminf(fmaxf(y0f + 1.0f, 0.0f), (float)(HH - 1));
            float wa = (1.0f - xw) * (1.0f - yw);
            float wb = (1.0f - xw) * yw;
            float wc = xw * (1.0f - yw);
            float wd = xw * yw;
            for (int c = 0; c < CC; ++c) {
                const float* pch = imgb + (size_t)c * HWSZ;
                float vv = wa * pch[y0 * WW + x0] + wb * pch[y1 * WW + x0]
                         + wc * pch[y0 * WW + x1] + wd * pch[y1 * WW + x1];
                outb[(size_t)c * HWSZ + hwp + i] = vv;  // same thread: ordered
            }
        }
    }
}

extern "C" void kernel_launch(void* const* d_in, const int* in_sizes, int n_in,
                              void* d_out, int out_size, void* d_ws, size_t ws_size,
                              hipStream_t stream)
{
    const float* img = (const float*)d_in[0];
    const float* flo = (const float*)d_in[1];
    float*       out = (float*)d_out;

    warp_bilinear_kernel<<<NBLOCKS, 256, 0, stream>>>(img, flo, out);
}

// Round 13
// 48.946 us; speedup vs baseline: 1.0295x; 1.0295x over previous
//
#include <hip/hip_runtime.h>

// Bilinear warp: out[b,c,h,w] = bilerp(img[b,c], (w+flo[b,0,h,w], h+flo[b,1,h,w]))
// img: [8,16,512,512] f32, flo: [8,2,512,512] f32, out: [8,16,512,512] f32.
//
// Round 13: single change vs R12: 512 threads (8 waves), 4 px/thread.
// Occupancy 12 -> 24 waves/CU (LDS 48KB -> 3 blocks/CU either way; twice the
// waves per block). Per-px VMEM identical (wave: 2 stage/ch + 1 store/ch +
// 2 flo). Tests the last un-falsified residual: latency hiding of the
// ds_read conflict stalls + barrier skew. Everything else = R12 (window
// 48x84 pitch-84 ox-skew, NBUF=3, 1 barrier/ch, counted vmcnt, NT stores,
// XCD-batch swizzle, badmask fixup).

#define BB 8
#define CC 16
#define HH 512
#define WW 512
#define HWSZ (HH * WW)

#define TW 64                    // output tile width
#define TH 32                    // output tile height
#define TILES_X (WW / TW)        // 8
#define TILES_Y (HH / TH)        // 16
#define TPI (TILES_X * TILES_Y)  // 128
#define NBLOCKS (BB * TPI)       // 1024 = 8 * 128 (XCD k <- batch k, bijective)
#define NXCD 8

#define HALO_T 7                 // top halo rows (window rows 48 = 7+32+9)
#define HALO_L 8                 // nominal left halo
#define LDS_PITCH 84             // floats per LDS row; row rr holds global
                                 //  cols [ox(rr), ox(rr)+83]
#define OXMAX (WW - LDS_PITCH)   // 428
#define WIN_ROWS 48              // rows 0..47 staged (48*84=4032)
#define PAD_FLOATS 4096          // 16 chunks * 256 floats (tail rows unread)
#define NBUF 3                   // triple buffer, single barrier per channel

typedef float f4 __attribute__((ext_vector_type(4)));

__device__ __forceinline__ void gload_lds16(const float* g, float* l) {
    // per-lane global src; wave-uniform LDS base, HW writes base + lane*16
    __builtin_amdgcn_global_load_lds(
        (const __attribute__((address_space(1))) void*)g,
        (__attribute__((address_space(3))) void*)l,
        16, 0, 0);
}

__global__ __launch_bounds__(512) void warp_bilinear_kernel(
    const float* __restrict__ img,
    const float* __restrict__ flo,
    float* __restrict__ out)
{
    __shared__ __align__(16) float lds[NBUF * PAD_FLOATS];   // 48 KB

    // XCD swizzle: XCD k <- batch k, tiles top-to-bottom.
    int bid = blockIdx.x;
    int wk  = (bid % NXCD) * (NBLOCKS / NXCD) + bid / NXCD;
    int b    = wk / TPI;
    int tile = wk - b * TPI;
    int ty   = tile / TILES_X;
    int tx   = tile - ty * TILES_X;

    int t    = threadIdx.x;
    int wv   = t >> 6;               // wave id 0..7
    int lane = t & 63;

    int r   = t >> 4;                // row in tile 0..31
    int c4  = (t & 15) << 2;         // col in tile, 4 px per thread
    int h   = ty * TH + r;
    int w0  = tx * TW + c4;
    int hw  = h * WW + w0;
    int wx0 = tx * TW - HALO_L;      // nominal window origin (may be <0)
    int wy0 = ty * TH - HALO_T;

    const float* imgb = img + (size_t)b * CC * HWSZ;
    float*       outb = out + (size_t)b * CC * HWSZ;

    // ---- flo loads FIRST: their implicit wait leaves prefetch in flight ---
    f4 fx4 = *(const f4*)(flo + (size_t)(b * 2 + 0) * HWSZ + hw);
    f4 fy4 = *(const f4*)(flo + (size_t)(b * 2 + 1) * HWSZ + hw);

    // ---- staging chunk setup: wave wv stages chunks {wv, wv+8} ------------
    // LDS float f: rr=f/84, cc=f%84 (mult of 4; 84%4==0 so 16B groups never
    // straddle rows). Row rr holds global cols [ox(rr), ox(rr)+83], all
    // in-bounds (ox<=428). Skew: ox = clamp(wx0-(rr&3)).
    const float* srcp[2];            // per-lane global src, channel 0
    int          loff[2];            // LDS float offset (wave-uniform)
    #pragma unroll
    for (int j = 0; j < 2; ++j) {
        int k  = wv + 8 * j;
        int f  = k * 256 + lane * 4;            // float idx in buffer (mult of 4)
        int rr = f / LDS_PITCH;                 // LDS row (rows >=48 unread)
        int cc = f - rr * LDS_PITCH;            // 0..80, mult of 4
        int gy = min(max(wy0 + rr, 0), HH - 1); // whole-row y clamp
        int ox = min(max(wx0 - (rr & 3), 0), OXMAX);   // skewed row origin
        srcp[j] = imgb + gy * WW + ox + cc;
        loff[j] = k * 256;
    }

    auto stage = [&](int ch, int buf) {
        const size_t choff = (size_t)ch * HWSZ;
        float* lbase = lds + buf * PAD_FLOATS;
        #pragma unroll
        for (int j = 0; j < 2; ++j)
            gload_lds16(srcp[j] + choff, lbase + loff[j]);
    };

    stage(0, 0);   // 2-deep prefetch in flight before any dependent work
    stage(1, 1);

    // ---- per-pixel precompute (overlaps stage latency) --------------------
    int   o0[4], o1[4];
    float wtx[4], wty[4], wbx[4], wby[4];
    int   badmask = 0;
    #pragma unroll
    for (int i = 0; i < 4; ++i) {
        float pos_x = (float)(w0 + i) + fx4[i];
        float pos_y = (float)h + fy4[i];

        float x0f = floorf(pos_x);
        float y0f = floorf(pos_y);
        float xw  = pos_x - x0f;     // weights from UNclamped floor (reference)
        float yw  = pos_y - y0f;

        int x0 = (int)fminf(fmaxf(x0f,        0.0f), (float)(WW - 1));
        int x1 = (int)fminf(fmaxf(x0f + 1.0f, 0.0f), (float)(WW - 1));
        int y0 = (int)fminf(fmaxf(y0f,        0.0f), (float)(HH - 1));
        int y1 = (int)fminf(fmaxf(y0f + 1.0f, 0.0f), (float)(HH - 1));

        int xb = min(x0, WW - 2);    // merged pair [xb, xb+1]

        float wa = (1.0f - xw) * (1.0f - yw);
        float wb = (1.0f - xw) * yw;
        float wc = xw * (1.0f - yw);
        float wd = xw * yw;

        float tx_ = (x0 == xb ? wa : 0.0f) + (x1 == xb ? wc : 0.0f);
        float bx_ = (x0 == xb ? wb : 0.0f) + (x1 == xb ? wd : 0.0f);
        wtx[i] = tx_;  wty[i] = (wa + wc) - tx_;
        wbx[i] = bx_;  wby[i] = (wb + wd) - bx_;

        int r0 = y0 - wy0, r1 = y1 - wy0;
        int ox0 = min(max(wx0 - (r0 & 3), 0), OXMAX);   // same formula as stage
        int ox1 = min(max(wx0 - (r1 & 3), 0), OXMAX);
        int s0 = xb - ox0, s1 = xb - ox1;
        bool ok = (s0 >= 0) & (s0 <= LDS_PITCH - 2)
                & (s1 >= 0) & (s1 <= LDS_PITCH - 2)
                & (r0 >= 0) & (r1 <= WIN_ROWS - 1);
        int a0 = r0 * LDS_PITCH + s0;
        int a1 = r1 * LDS_PITCH + s1;
        if (!ok) { a0 = 0; a1 = 0; badmask |= (1 << i); }  // safe dummy; fixed up
        o0[i] = a0;  o1[i] = a1;
    }

    // ---- channel loop: ONE barrier per channel, stage 2 ahead -------------
    // Per-wave VMEM issue: [flo x2][stage0 x2][stage1 x2] | iter c: store(c),
    // stage(c+2) x2. At iter-c wait, ops newer than stage(c):
    //   c==0 : stage(1) x2                    -> vmcnt(2)
    //   1..14: store(c-1) + stage(c+1) x2 = 3 -> vmcnt(3)  (store in flight)
    //   c==15: store(14)                      -> vmcnt(1)
    #pragma unroll
    for (int c = 0; c < CC; ++c) {
        const int buf = c % NBUF;

        if (c == 0)          asm volatile("s_waitcnt vmcnt(2)" ::: "memory");
        else if (c < CC - 1) asm volatile("s_waitcnt vmcnt(3)" ::: "memory");
        else                 asm volatile("s_waitcnt vmcnt(1)" ::: "memory");
        asm volatile("s_waitcnt lgkmcnt(0)" ::: "memory"); // reads of c-1 drained
        __builtin_amdgcn_sched_barrier(0);
        __builtin_amdgcn_s_barrier();   // stage(c) visible AND all waves done
                                        // reading buf((c-1)%3)

        const float* cur = lds + buf * PAD_FLOATS;
        f4 v;
        #pragma unroll
        for (int i = 0; i < 4; ++i) {
            float t0 = cur[o0[i]];
            float t1 = cur[o0[i] + 1];
            float u0 = cur[o1[i]];
            float u1 = cur[o1[i] + 1];
            v[i] = wtx[i] * t0 + wty[i] * t1 + wbx[i] * u0 + wby[i] * u1;
        }
        __builtin_nontemporal_store(v, (f4*)(outb + (size_t)c * HWSZ + hw));

        if (c + 2 < CC) stage(c + 2, (c + 2) % NBUF);  // overwrites buf((c-1)%3)
    }

    // ---- fixup: pixels whose footprint missed the staged window (~never) ---
    if (__builtin_expect(badmask != 0, 0)) {
        #pragma unroll
        for (int i = 0; i < 4; ++i) if (badmask & (1 << i)) {
            float fx = flo[(size_t)(b * 2 + 0) * HWSZ + hw + i];
            float fy = flo[(size_t)(b * 2 + 1) * HWSZ + hw + i];
            float pos_x = (float)(w0 + i) + fx;
            float pos_y = (float)h + fy;
            float x0f = floorf(pos_x), y0f = floorf(pos_y);
            float xw = pos_x - x0f,   yw = pos_y - y0f;
            int x0 = (int)fminf(fmaxf(x0f,        0.0f), (float)(WW - 1));
            int x1 = (int)fminf(fmaxf(x0f + 1.0f, 0.0f), (float)(WW - 1));
            int y0 = (int)fminf(fmaxf(y0f,        0.0f), (float)(HH - 1));
            int y1 = (int)fminf(fmaxf(y0f + 1.0f, 0.0f), (float)(HH - 1));
            float wa = (1.0f - xw) * (1.0f - yw);
            float wb = (1.0f - xw) * yw;
            float wc = xw * (1.0f - yw);
            float wd = xw * yw;
            for (int c = 0; c < CC; ++c) {
                const float* p = imgb + (size_t)c * HWSZ;
                float vv = wa * p[y0 * WW + x0] + wb * p[y1 * WW + x0]
                         + wc * p[y0 * WW + x1] + wd * p[y1 * WW + x1];
                outb[(size_t)c * HWSZ + hw + i] = vv;   // same thread: ordered
            }
        }
    }
}

extern "C" void kernel_launch(void* const* d_in, const int* in_sizes, int n_in,
                              void* d_out, int out_size, void* d_ws, size_t ws_size,
                              hipStream_t stream)
{
    const float* img = (const float*)d_in[0];
    const float* flo = (const float*)d_in[1];
    float*       out = (float*)d_out;

    warp_bilinear_kernel<<<NBLOCKS, 512, 0, stream>>>(img, flo, out);
}